// Round 1
// baseline (478.994 us; speedup 1.0000x reference)
//
#include <hip/hip_runtime.h>
#include <hip/hip_bf16.h>

// Per-degree affine (11 grouped GEMMs) + fused segment-sum pooling.
// atoms (N,128) f32 -> bf16 MFMA vs W[deg] (128,128) -> +b[deg] -> atomicAdd
// into pooled (4096,128) f32.
//
// Tiles: 64 rows x 128 cols per block (256 thr = 4 waves, 16 rows/wave).
// Tiles never straddle a degree boundary (split per degree on device from
// deg_slice), so each block uses a single W[k].

#define TM 64
#define LDA 136   // bf16 elems; 272 B row stride: 16B-aligned, ~conflict-free b128 reads
#define LDW 136

typedef short bf16x8 __attribute__((ext_vector_type(8)));
typedef float f32x4  __attribute__((ext_vector_type(4)));

__device__ __forceinline__ unsigned short f2bf(float f) {
    // round-to-nearest-even f32 -> bf16 (inputs are finite normals)
    unsigned int u = __builtin_bit_cast(unsigned int, f);
    u += 0x7fffu + ((u >> 16) & 1u);
    return (unsigned short)(u >> 16);
}

__global__ __launch_bounds__(256, 2) void degree_affine_pool(
    const float* __restrict__ atoms,
    const float* __restrict__ W,
    const float* __restrict__ bias,
    const int*   __restrict__ deg_slice,
    const int*   __restrict__ membership,
    float*       __restrict__ out,
    int K)
{
    __shared__ unsigned short Alds[TM * LDA];    // 17408 B
    __shared__ unsigned short Wlds[128 * LDW];   // 34816 B, stored transposed: [c][f]

    const int bid = blockIdx.x;
    const int tid = threadIdx.x;

    // map block -> (degree k, tile index within degree block)
    int k = -1, tile = 0, acc_t = 0;
    for (int kk = 0; kk < K; ++kk) {
        int c  = deg_slice[2 * kk + 1];
        int nt = (c + TM - 1) >> 6;
        if (k < 0 && bid < acc_t + nt) { k = kk; tile = bid - acc_t; }
        acc_t += nt;
    }
    if (k < 0) return;                       // past the last real tile
    const int start      = deg_slice[2 * k];
    const int cnt        = deg_slice[2 * k + 1];
    const int row0       = start + tile * TM;
    const int rows_valid = min(TM, cnt - tile * TM);

    // ---- stage A tile (64 x 128 f32 -> bf16), coalesced float4 reads ----
    for (int e = tid; e < TM * 32; e += 256) {
        int r = e >> 5, f4 = e & 31;
        float4 v = make_float4(0.f, 0.f, 0.f, 0.f);
        if (r < rows_valid)
            v = *reinterpret_cast<const float4*>(atoms + (size_t)(row0 + r) * 128 + f4 * 4);
        unsigned int lo = (unsigned int)f2bf(v.x) | ((unsigned int)f2bf(v.y) << 16);
        unsigned int hi = (unsigned int)f2bf(v.z) | ((unsigned int)f2bf(v.w) << 16);
        *reinterpret_cast<uint2*>(&Alds[r * LDA + f4 * 4]) = make_uint2(lo, hi);
    }

    // ---- stage W[k] transposed into LDS: Wlds[c][f] (bf16) ----
    const float* Wk = W + (size_t)k * 128 * 128;
    for (int e = tid; e < 128 * 64; e += 256) {
        int c = e & 127, f2 = e >> 7;            // c fast -> coalesced global reads
        float w0 = Wk[(2 * f2)     * 128 + c];
        float w1 = Wk[(2 * f2 + 1) * 128 + c];
        unsigned int p = (unsigned int)f2bf(w0) | ((unsigned int)f2bf(w1) << 16);
        *reinterpret_cast<unsigned int*>(&Wlds[c * LDW + 2 * f2]) = p;
    }
    __syncthreads();

    const int wave = tid >> 6;
    const int lane = tid & 63;
    const int quad = lane >> 4;
    const int cb   = lane & 15;

    f32x4 acc[8];
    #pragma unroll
    for (int ct = 0; ct < 8; ++ct) acc[ct] = (f32x4){0.f, 0.f, 0.f, 0.f};

    // ---- K loop: 4 steps of 32, 8 column tiles of 16 ----
    #pragma unroll
    for (int k0 = 0; k0 < 128; k0 += 32) {
        bf16x8 af = *reinterpret_cast<const bf16x8*>(
            &Alds[(wave * 16 + cb) * LDA + k0 + quad * 8]);
        #pragma unroll
        for (int ct = 0; ct < 8; ++ct) {
            bf16x8 bf = *reinterpret_cast<const bf16x8*>(
                &Wlds[(ct * 16 + cb) * LDW + k0 + quad * 8]);
            acc[ct] = __builtin_amdgcn_mfma_f32_16x16x32_bf16(af, bf, acc[ct], 0, 0, 0);
        }
    }

    // ---- epilogue: + bias, scatter-add rows into pooled[membership] ----
    int  segs[4];
    bool valid[4];
    #pragma unroll
    for (int reg = 0; reg < 4; ++reg) {
        int rl = wave * 16 + quad * 4 + reg;     // local row this lane holds
        valid[reg] = (rl < rows_valid);
        segs[reg]  = valid[reg] ? membership[row0 + rl] : 0;
    }
    const float* bk = bias + k * 128;
    #pragma unroll
    for (int ct = 0; ct < 8; ++ct) {
        int   col = ct * 16 + cb;
        float bv  = bk[col];
        #pragma unroll
        for (int reg = 0; reg < 4; ++reg) {
            if (valid[reg]) {
                __hip_atomic_fetch_add(out + (size_t)segs[reg] * 128 + col,
                                       acc[ct][reg] + bv,
                                       __ATOMIC_RELAXED, __HIP_MEMORY_SCOPE_AGENT);
            }
        }
    }
}

extern "C" void kernel_launch(void* const* d_in, const int* in_sizes, int n_in,
                              void* d_out, int out_size, void* d_ws, size_t ws_size,
                              hipStream_t stream) {
    const float* atoms = (const float*)d_in[0];
    const float* W     = (const float*)d_in[1];
    const float* bias  = (const float*)d_in[2];
    const int*   deg   = (const int*)d_in[3];
    const int*   mem   = (const int*)d_in[4];
    float*       out   = (float*)d_out;

    const int K = in_sizes[3] / 2;       // 11
    const int N = in_sizes[0] / 128;     // 393216

    // harness poisons d_out with 0xAA; atomics need zeros
    (void)hipMemsetAsync(d_out, 0, (size_t)out_size * sizeof(float), stream);

    const int blocks = (N + TM - 1) / TM + K;   // upper bound incl. boundary splits
    degree_affine_pool<<<blocks, 256, 0, stream>>>(atoms, W, bias, deg, mem, out, K);
}

// Round 2
// 423.555 us; speedup vs baseline: 1.1309x; 1.1309x over previous
//
#include <hip/hip_runtime.h>
#include <hip/hip_bf16.h>

// Per-degree affine + segment pooling, restructured via linearity:
//   pooled[s] = sum_k ( S[s,k,:] @ W[k] ) + sum_k count[s,k]*b[k]
// where S[s,k,:] = sum of atom rows in segment s with degree k.
//
// Pipeline (all on `stream`):
//   memset  : zero hist+cursor
//   k_hist  : histogram of keys (s*K + deg)            393K cheap atomics
//   k_scan  : exclusive scan -> binstart[45057]        1 block
//   k_scatter: counting-sort atom indices into ws idx  393K cheap atomics
//   k_wconv : W f32 -> bf16 transposed [k][col][f]
//   k_phaseA: gather rows per segment, register-sum -> S (bf16), bsum (f32)
//   k_phaseB: MFMA GEMM out = S @ Wb + bsum  (no atomics, plain stores)

typedef short bf16x8 __attribute__((ext_vector_type(8)));
typedef float f32x4  __attribute__((ext_vector_type(4)));

__device__ __forceinline__ unsigned short f2bf(float f) {
    unsigned int u = __builtin_bit_cast(unsigned int, f);
    u += 0x7fffu + ((u >> 16) & 1u);
    return (unsigned short)(u >> 16);
}

__device__ __forceinline__ int deg_of(int i, const int* __restrict__ ds, int K) {
    int k = 0, end = 0;
    for (int kk = 0; kk < K; ++kk) { end += ds[2 * kk + 1]; k += (i >= end) ? 1 : 0; }
    return k;
}

__global__ __launch_bounds__(256) void k_hist(
    const int* __restrict__ mem, const int* __restrict__ ds,
    unsigned* __restrict__ hist, int N, int K)
{
    int i = blockIdx.x * 256 + threadIdx.x;
    if (i >= N) return;
    int key = mem[i] * K + deg_of(i, ds, K);
    atomicAdd(&hist[key], 1u);
}

__global__ __launch_bounds__(1024) void k_scan(
    const unsigned* __restrict__ hist, unsigned* __restrict__ binstart, int B, int K)
{
    __shared__ unsigned segsum[4096];
    __shared__ unsigned aux[1024];
    int t = threadIdx.x;
    int CH = (B + 1023) >> 10;
    unsigned loc = 0;
    for (int j = 0; j < CH; ++j) {
        int s = t * CH + j;
        unsigned tot = 0;
        if (s < B) {
            for (int k = 0; k < K; ++k) tot += hist[s * K + k];
            segsum[s] = tot;
        }
        loc += tot;
    }
    aux[t] = loc;
    __syncthreads();
    for (int d = 1; d < 1024; d <<= 1) {          // Hillis-Steele inclusive scan
        unsigned v = (t >= d) ? aux[t - d] : 0u;
        __syncthreads();
        aux[t] += v;
        __syncthreads();
    }
    unsigned run = (t > 0) ? aux[t - 1] : 0u;     // exclusive base for this chunk
    for (int j = 0; j < CH; ++j) {
        int s = t * CH + j;
        if (s < B) {
            unsigned b2 = run;
            for (int k = 0; k < K; ++k) { binstart[s * K + k] = b2; b2 += hist[s * K + k]; }
            run = b2;
        }
    }
    if (t == 1023) binstart[(size_t)B * K] = run;  // == N
}

__global__ __launch_bounds__(256) void k_scatter(
    const int* __restrict__ mem, const int* __restrict__ ds,
    const unsigned* __restrict__ binstart, unsigned* __restrict__ cursor,
    unsigned* __restrict__ idx, int N, int K)
{
    int i = blockIdx.x * 256 + threadIdx.x;
    if (i >= N) return;
    int key = mem[i] * K + deg_of(i, ds, K);
    unsigned p = atomicAdd(&cursor[key], 1u);
    idx[binstart[key] + p] = (unsigned)i;
}

// W[k][f][c] f32  ->  Wb[k][c][f] bf16 (transposed via LDS)
__global__ __launch_bounds__(256) void k_wconv(
    const float* __restrict__ W, unsigned short* __restrict__ Wb)
{
    __shared__ unsigned short t[128 * 130];
    int k = blockIdx.x;
    const float* Wk = W + (size_t)k * 16384;
    unsigned short* Wbk = Wb + (size_t)k * 16384;
    for (int e = threadIdx.x; e < 16384; e += 256) {
        int f = e >> 7, c = e & 127;
        t[f * 130 + c] = f2bf(Wk[e]);
    }
    __syncthreads();
    for (int e = threadIdx.x; e < 16384; e += 256) {
        int c = e >> 7, f = e & 127;
        Wbk[e] = t[f * 130 + c];
    }
}

// One block per segment; 128 threads = one feature each. Register-only
// accumulation; S written bf16; bsum[s][f] = sum_k count*bias.
__global__ __launch_bounds__(128) void k_phaseA(
    const float* __restrict__ atoms, const float* __restrict__ bias,
    const unsigned* __restrict__ binstart, const unsigned* __restrict__ idx,
    unsigned short* __restrict__ S, float* __restrict__ bsum, int K)
{
    int s = blockIdx.x, f = threadIdx.x;
    float bs = 0.f;
    for (int k = 0; k < K; ++k) {
        unsigned st = binstart[s * K + k];
        unsigned en = binstart[s * K + k + 1];
        float a0 = 0.f, a1 = 0.f, a2 = 0.f, a3 = 0.f;
        unsigned j = st;
        for (; j + 4 <= en; j += 4) {             // 4-way MLP
            unsigned r0 = idx[j], r1 = idx[j + 1], r2 = idx[j + 2], r3 = idx[j + 3];
            a0 += atoms[(size_t)r0 * 128 + f];
            a1 += atoms[(size_t)r1 * 128 + f];
            a2 += atoms[(size_t)r2 * 128 + f];
            a3 += atoms[(size_t)r3 * 128 + f];
        }
        for (; j < en; ++j) a0 += atoms[(size_t)idx[j] * 128 + f];
        float acc = (a0 + a1) + (a2 + a3);
        S[(size_t)(s * K + k) * 128 + f] = f2bf(acc);
        bs += (float)(en - st) * bias[k * 128 + f];
    }
    bsum[(size_t)s * 128 + f] = bs;
}

// One wave per (16 segments x 32 cols) tile; K-chain = K*128 (=1408).
// Direct global reads (S HBM-once, Wb L2-hot), plain stores, no LDS/atomics.
__global__ __launch_bounds__(64) void k_phaseB(
    const unsigned short* __restrict__ S,   // [B][K*128] bf16
    const unsigned short* __restrict__ Wb,  // [K][128][128] bf16 ([k][col][f])
    const float* __restrict__ bsum,         // [B][128]
    float* __restrict__ out,                // [B][128]
    int K)
{
    int bx   = blockIdx.x;
    int s0   = (bx >> 2) * 16;
    int c0   = (bx & 3) * 32;
    int lane = threadIdx.x;
    int quad = lane >> 4, cb = lane & 15;

    const int KD = K * 128;
    f32x4 acc0 = (f32x4){0.f, 0.f, 0.f, 0.f};
    f32x4 acc1 = (f32x4){0.f, 0.f, 0.f, 0.f};

    const unsigned short* Arow = S  + (size_t)(s0 + cb) * KD + quad * 8;
    const unsigned short* B0   = Wb + (size_t)(c0 + cb)      * 128 + quad * 8;
    const unsigned short* B1   = Wb + (size_t)(c0 + 16 + cb) * 128 + quad * 8;

    #pragma unroll 1
    for (int kk = 0; kk < K; ++kk) {
        #pragma unroll
        for (int k0 = 0; k0 < 128; k0 += 32) {
            bf16x8 a  = *reinterpret_cast<const bf16x8*>(Arow + kk * 128 + k0);
            bf16x8 b0 = *reinterpret_cast<const bf16x8*>(B0 + (size_t)kk * 16384 + k0);
            bf16x8 b1 = *reinterpret_cast<const bf16x8*>(B1 + (size_t)kk * 16384 + k0);
            acc0 = __builtin_amdgcn_mfma_f32_16x16x32_bf16(a, b0, acc0, 0, 0, 0);
            acc1 = __builtin_amdgcn_mfma_f32_16x16x32_bf16(a, b1, acc1, 0, 0, 0);
        }
    }
    #pragma unroll
    for (int reg = 0; reg < 4; ++reg) {
        int s = s0 + quad * 4 + reg;
        int c = c0 + cb;
        out[(size_t)s * 128 + c]      = acc0[reg] + bsum[(size_t)s * 128 + c];
        out[(size_t)s * 128 + c + 16] = acc1[reg] + bsum[(size_t)s * 128 + c + 16];
    }
}

// ---------------- fallback (round-1 fused kernel) if ws too small ----------
#define TM 64
#define LDA 136
#define LDW 136
__global__ __launch_bounds__(256, 2) void degree_affine_pool(
    const float* __restrict__ atoms, const float* __restrict__ W,
    const float* __restrict__ bias, const int* __restrict__ deg_slice,
    const int* __restrict__ membership, float* __restrict__ out, int K)
{
    __shared__ unsigned short Alds[TM * LDA];
    __shared__ unsigned short Wlds[128 * LDW];
    const int bid = blockIdx.x, tid = threadIdx.x;
    int k = -1, tile = 0, acc_t = 0;
    for (int kk = 0; kk < K; ++kk) {
        int c = deg_slice[2 * kk + 1];
        int nt = (c + TM - 1) >> 6;
        if (k < 0 && bid < acc_t + nt) { k = kk; tile = bid - acc_t; }
        acc_t += nt;
    }
    if (k < 0) return;
    const int start = deg_slice[2 * k], cnt = deg_slice[2 * k + 1];
    const int row0 = start + tile * TM;
    const int rows_valid = min(TM, cnt - tile * TM);
    for (int e = tid; e < TM * 32; e += 256) {
        int r = e >> 5, f4 = e & 31;
        float4 v = make_float4(0.f, 0.f, 0.f, 0.f);
        if (r < rows_valid)
            v = *reinterpret_cast<const float4*>(atoms + (size_t)(row0 + r) * 128 + f4 * 4);
        unsigned lo = (unsigned)f2bf(v.x) | ((unsigned)f2bf(v.y) << 16);
        unsigned hi = (unsigned)f2bf(v.z) | ((unsigned)f2bf(v.w) << 16);
        *reinterpret_cast<uint2*>(&Alds[r * LDA + f4 * 4]) = make_uint2(lo, hi);
    }
    const float* Wk = W + (size_t)k * 16384;
    for (int e = tid; e < 8192; e += 256) {
        int c = e & 127, f2 = e >> 7;
        unsigned p = (unsigned)f2bf(Wk[(2 * f2) * 128 + c]) |
                     ((unsigned)f2bf(Wk[(2 * f2 + 1) * 128 + c]) << 16);
        *reinterpret_cast<unsigned*>(&Wlds[c * LDW + 2 * f2]) = p;
    }
    __syncthreads();
    const int wave = tid >> 6, lane = tid & 63, quad = lane >> 4, cb = lane & 15;
    f32x4 acc[8];
    #pragma unroll
    for (int ct = 0; ct < 8; ++ct) acc[ct] = (f32x4){0.f, 0.f, 0.f, 0.f};
    #pragma unroll
    for (int k0 = 0; k0 < 128; k0 += 32) {
        bf16x8 af = *reinterpret_cast<const bf16x8*>(&Alds[(wave * 16 + cb) * LDA + k0 + quad * 8]);
        #pragma unroll
        for (int ct = 0; ct < 8; ++ct) {
            bf16x8 bf = *reinterpret_cast<const bf16x8*>(&Wlds[(ct * 16 + cb) * LDW + k0 + quad * 8]);
            acc[ct] = __builtin_amdgcn_mfma_f32_16x16x32_bf16(af, bf, acc[ct], 0, 0, 0);
        }
    }
    int segs[4]; bool valid[4];
    #pragma unroll
    for (int reg = 0; reg < 4; ++reg) {
        int rl = wave * 16 + quad * 4 + reg;
        valid[reg] = (rl < rows_valid);
        segs[reg] = valid[reg] ? membership[row0 + rl] : 0;
    }
    const float* bk = bias + k * 128;
    #pragma unroll
    for (int ct = 0; ct < 8; ++ct) {
        int col = ct * 16 + cb;
        float bv = bk[col];
        #pragma unroll
        for (int reg = 0; reg < 4; ++reg)
            if (valid[reg])
                __hip_atomic_fetch_add(out + (size_t)segs[reg] * 128 + col,
                                       acc[ct][reg] + bv, __ATOMIC_RELAXED,
                                       __HIP_MEMORY_SCOPE_AGENT);
    }
}
// ---------------------------------------------------------------------------

static inline size_t aln(size_t x) { return (x + 255) & ~(size_t)255; }

extern "C" void kernel_launch(void* const* d_in, const int* in_sizes, int n_in,
                              void* d_out, int out_size, void* d_ws, size_t ws_size,
                              hipStream_t stream) {
    const float* atoms = (const float*)d_in[0];
    const float* W     = (const float*)d_in[1];
    const float* bias  = (const float*)d_in[2];
    const int*   deg   = (const int*)d_in[3];
    const int*   mem   = (const int*)d_in[4];
    float*       out   = (float*)d_out;

    const int K = in_sizes[3] / 2;       // 11
    const int N = in_sizes[0] / 128;     // 393216
    const int B = out_size / 128;        // 4096

    // workspace plan
    size_t oWb   = 0;                         size_t sWb   = (size_t)K * 16384 * 2;
    size_t oHist = aln(oWb + sWb);            size_t sHist = (size_t)B * K * 4;
    size_t oCur  = oHist + sHist;             size_t sCur  = sHist;   // contiguous w/ hist
    size_t oBin  = aln(oCur + sCur);          size_t sBin  = ((size_t)B * K + 1) * 4;
    size_t oIdx  = aln(oBin + sBin);          size_t sIdx  = (size_t)N * 4;
    size_t oBsum = aln(oIdx + sIdx);          size_t sBsum = (size_t)B * 128 * 4;
    size_t oS    = aln(oBsum + sBsum);        size_t sS    = (size_t)B * K * 128 * 2;
    size_t total = oS + sS;                   // ~16.1 MB

    if (ws_size < total || B > 4096) {
        // fallback: round-1 fused kernel with global atomics
        (void)hipMemsetAsync(d_out, 0, (size_t)out_size * sizeof(float), stream);
        const int blocks = (N + TM - 1) / TM + K;
        degree_affine_pool<<<blocks, 256, 0, stream>>>(atoms, W, bias, deg, mem, out, K);
        return;
    }

    char* ws = (char*)d_ws;
    unsigned short* Wb   = (unsigned short*)(ws + oWb);
    unsigned*       hist = (unsigned*)(ws + oHist);
    unsigned*       cur  = (unsigned*)(ws + oCur);
    unsigned*       bin  = (unsigned*)(ws + oBin);
    unsigned*       idx  = (unsigned*)(ws + oIdx);
    float*          bsum = (float*)(ws + oBsum);
    unsigned short* S    = (unsigned short*)(ws + oS);

    (void)hipMemsetAsync(hist, 0, sHist + sCur, stream);   // hist + cursor

    const int nb = (N + 255) / 256;
    k_hist   <<<nb, 256, 0, stream>>>(mem, deg, hist, N, K);
    k_scan   <<<1, 1024, 0, stream>>>(hist, bin, B, K);
    k_scatter<<<nb, 256, 0, stream>>>(mem, deg, bin, cur, idx, N, K);
    k_wconv  <<<K, 256, 0, stream>>>(W, Wb);
    k_phaseA <<<B, 128, 0, stream>>>(atoms, bias, bin, idx, S, bsum, K);
    k_phaseB <<<(B / 16) * 4, 64, 0, stream>>>(S, Wb, bsum, out, K);
}